// Round 4
// baseline (26869.882 us; speedup 1.0000x reference)
//
#include <hip/hip_runtime.h>
#include <hip/hip_bf16.h>
#include <math.h>

#define E_ 7
#define B_ 50
#define T_ 100
#define D_ 128
#define A_ 32
#define L_ 256
#define H_ 1024
#define C_ 128
#define EB_ 350
#define TB_ 5000
#define SQRTH 0.31622776601683794f
#define NWG 256

typedef __attribute__((ext_vector_type(8))) short s8v;
typedef __attribute__((ext_vector_type(4))) float f32x4;
typedef _Float16 f16x2 __attribute__((ext_vector_type(2)));
typedef __hip_bfloat16 bf16;

struct BG {
  const bf16* A[8];
  const bf16* W[8];
  const float* bias[8];
  float* Cf[8];
  bf16* Cb[8];
};

// ---------------- bf16 MFMA GEMM (validated round 2) ----------------
template<int BM, int ACT, int OUT>
__global__ __launch_bounds__(256)
void bgemm(BG g, int M, int K, int lda, int ldw, int ldc) {
  __shared__ short As[BM * 64];
  __shared__ short Ws[128 * 64];
  const short* Ap = (const short*)g.A[blockIdx.z];
  const short* Wp = (const short*)g.W[blockIdx.z];
  const int bm = blockIdx.x * BM, bn = blockIdx.y * 128;
  const int tid = threadIdx.x;
  const int wv = tid >> 6, lane = tid & 63;
  const int wm0 = (wv >> 1) * (BM / 2), wn0 = (wv & 1) * 64;
  const int l15 = lane & 15, l4 = lane >> 4;
  constexpr int FM = BM / 32;
  constexpr int AI = BM / 32;
  f32x4 acc[FM][4] = {};
  for (int k0 = 0; k0 < K; k0 += 64) {
    s8v av[AI], wvv[4];
#pragma unroll
    for (int i = 0; i < AI; ++i) {
      const int c = tid + i * 256, r = c >> 3, ck = c & 7;
      s8v v = {};
      if (bm + r < M) v = *(const s8v*)(Ap + (size_t)(bm + r) * lda + k0 + ck * 8);
      av[i] = v;
    }
#pragma unroll
    for (int i = 0; i < 4; ++i) {
      const int c = tid + i * 256, r = c >> 3, ck = c & 7;
      wvv[i] = *(const s8v*)(Wp + (size_t)(bn + r) * ldw + k0 + ck * 8);
    }
    __syncthreads();
#pragma unroll
    for (int i = 0; i < AI; ++i) {
      const int c = tid + i * 256, r = c >> 3, ck = c & 7;
      *(s8v*)(As + r * 64 + ((ck ^ (r & 7)) << 3)) = av[i];
    }
#pragma unroll
    for (int i = 0; i < 4; ++i) {
      const int c = tid + i * 256, r = c >> 3, ck = c & 7;
      *(s8v*)(Ws + r * 64 + ((ck ^ (r & 7)) << 3)) = wvv[i];
    }
    __syncthreads();
#pragma unroll
    for (int ks = 0; ks < 2; ++ks) {
      s8v af[FM], bfr[4];
#pragma unroll
      for (int m = 0; m < FM; ++m) {
        const int r = wm0 + m * 16 + l15, ck = ks * 4 + l4;
        af[m] = *(const s8v*)(As + r * 64 + ((ck ^ (r & 7)) << 3));
      }
#pragma unroll
      for (int n = 0; n < 4; ++n) {
        const int r = wn0 + n * 16 + l15, ck = ks * 4 + l4;
        bfr[n] = *(const s8v*)(Ws + r * 64 + ((ck ^ (r & 7)) << 3));
      }
#pragma unroll
      for (int m = 0; m < FM; ++m)
#pragma unroll
        for (int n = 0; n < 4; ++n)
          acc[m][n] = __builtin_amdgcn_mfma_f32_16x16x32_bf16(af[m], bfr[n], acc[m][n], 0, 0, 0);
    }
    __syncthreads();
  }
  const float* bias = g.bias[blockIdx.z];
  float* Cf = g.Cf[blockIdx.z];
  bf16* Cb = g.Cb[blockIdx.z];
#pragma unroll
  for (int n = 0; n < 4; ++n) {
    const int col = bn + wn0 + n * 16 + l15;
    const float bv = bias ? bias[col] : 0.f;
#pragma unroll
    for (int m = 0; m < FM; ++m) {
#pragma unroll
      for (int j = 0; j < 4; ++j) {
        const int row = bm + wm0 + m * 16 + l4 * 4 + j;
        if (row < M) {
          float v = acc[m][n][j] + bv;
          if (ACT == 1) v = fmaxf(v, 0.f);
          if (ACT == 2) v = tanhf(v);
          if (OUT == 0) Cf[(size_t)row * ldc + col] = v;
          if (OUT == 1) Cb[(size_t)row * ldc + col] = __float2bfloat16(v);
        }
      }
    }
  }
}

// ---------------- conversions ----------------
__global__ __launch_bounds__(256)
void cvtT_kernel(const float* __restrict__ src, bf16* __restrict__ dst,
                 int K, int N, long ss, long ds) {
  __shared__ float t[32][33];
  src += (size_t)blockIdx.z * ss;
  dst += (size_t)blockIdx.z * ds;
  const int n0 = blockIdx.x * 32, k0 = blockIdx.y * 32;
  const int tx = threadIdx.x & 31, ty = threadIdx.x >> 5;
#pragma unroll
  for (int i = 0; i < 4; ++i)
    t[ty + 8 * i][tx] = src[(size_t)(k0 + ty + 8 * i) * N + n0 + tx];
  __syncthreads();
#pragma unroll
  for (int i = 0; i < 4; ++i)
    dst[(size_t)(n0 + ty + 8 * i) * K + k0 + tx] = __float2bfloat16(t[tx][ty + 8 * i]);
}

struct B4 { bf16 a, b, c, d; };
__global__ __launch_bounds__(256)
void cvt_kernel(const float* __restrict__ s, bf16* __restrict__ d, int n4) {
  const int i = blockIdx.x * 256 + threadIdx.x;
  if (i < n4) {
    const float4 v = ((const float4*)s)[i];
    B4 o = {__float2bfloat16(v.x), __float2bfloat16(v.y),
            __float2bfloat16(v.z), __float2bfloat16(v.w)};
    ((B4*)d)[i] = o;
  }
}

__global__ __launch_bounds__(256)
void ax_build(const float* __restrict__ actions, const float* __restrict__ xs,
              bf16* __restrict__ dst) {
  const int idx = blockIdx.x * 256 + threadIdx.x;
  if (idx >= E_ * TB_ * 192) return;
  const int k = idx % 192;
  const int r = (idx / 192) % TB_;
  const int e = idx / (192 * TB_);
  float v = 0.f;
  if (k < 32) v = actions[((size_t)e * TB_ + r) * A_ + k];
  else if (k < 160) v = xs[((size_t)e * TB_ + r) * D_ + (k - 32)];
  dst[idx] = __float2bfloat16(v);
}

__global__ __launch_bounds__(256)
void waxT_build(const float* __restrict__ act_w, bf16* __restrict__ dst) {
  const int idx = blockIdx.x * 256 + threadIdx.x;
  if (idx >= E_ * 256 * 192) return;
  const int k = idx % 192;
  const int n = (idx / 192) % 256;
  const int e = idx / (192 * 256);
  float v = (k < 160) ? act_w[(size_t)e * 416 * 256 + (size_t)(256 + k) * 256 + n] : 0.f;
  dst[idx] = __float2bfloat16(v);
}

__global__ __launch_bounds__(256)
void wsplitT_build(const float* __restrict__ act_w, bf16* __restrict__ hi,
                   bf16* __restrict__ lo) {
  const int idx = blockIdx.x * 256 + threadIdx.x;
  if (idx >= E_ * 256 * 256) return;
  const int k = idx & 255;
  const int n = (idx >> 8) & 255;
  const int e = idx >> 16;
  const float w = act_w[(size_t)e * 416 * 256 + (size_t)k * 256 + n];
  const bf16 h = __float2bfloat16(w);
  hi[idx] = h;
  lo[idx] = __float2bfloat16(w - __bfloat162float(h));
}

// ---------------- q/KL (+z0 split hi/lo) ----------------
__global__ __launch_bounds__(256)
void qkl_kernel(const float* __restrict__ ctx, int rows, int row_off, int ctx_estride,
                const float* __restrict__ qw, const float* __restrict__ qb,
                const float* __restrict__ pm, const float* __restrict__ pl,
                const float* __restrict__ eps0, bf16* __restrict__ z0hi,
                bf16* __restrict__ z0lo, float* __restrict__ logqp) {
  __shared__ float cx[16][128];
  __shared__ float red[16];
  const int e = blockIdx.y;
  const int r0 = blockIdx.x * 16;
  const int tid = threadIdx.x;
  {
    const int r = tid >> 4, c = (tid & 15) * 8;
    float4 v0 = make_float4(0.f, 0.f, 0.f, 0.f), v1 = v0;
    if (r0 + r < rows) {
      const float* src = ctx + (size_t)e * ctx_estride + (size_t)(r0 + r) * C_ + c;
      v0 = *(const float4*)src;
      v1 = *(const float4*)(src + 4);
    }
    *(float4*)&cx[r][c] = v0;
    *(float4*)&cx[r][c + 4] = v1;
  }
  if (tid < 16) red[tid] = 0.f;
  __syncthreads();
  const int j = tid;
  const float* w = qw + (size_t)e * C_ * 512;
  float am_[16] = {};
  float al_[16] = {};
  for (int k0 = 0; k0 < C_; k0 += 4) {
    float wm[4], wl[4];
#pragma unroll
    for (int q = 0; q < 4; ++q) {
      wm[q] = w[(size_t)(k0 + q) * 512 + j];
      wl[q] = w[(size_t)(k0 + q) * 512 + 256 + j];
    }
#pragma unroll
    for (int r = 0; r < 16; ++r) {
      const float4 cv = *(const float4*)&cx[r][k0];
      const float cc[4] = {cv.x, cv.y, cv.z, cv.w};
#pragma unroll
      for (int q = 0; q < 4; ++q) {
        am_[r] = fmaf(cc[q], wm[q], am_[r]);
        al_[r] = fmaf(cc[q], wl[q], al_[r]);
      }
    }
  }
  const float qbm = qb[(size_t)e * 512 + j];
  const float qbl = qb[(size_t)e * 512 + 256 + j];
  const float pmv = pm[(size_t)e * L_ + j];
  const float plv = pl[(size_t)e * L_ + j];
  const float inv2e = 0.5f * expf(-2.f * plv);
#pragma unroll
  for (int r = 0; r < 16; ++r) {
    float kl = 0.f;
    if (r0 + r < rows) {
      const float qm_ = am_[r] + qbm;
      const float ql_ = al_[r] + qbl;
      const float dm = qm_ - pmv;
      kl = plv - ql_ + (expf(2.f * ql_) + dm * dm) * inv2e - 0.5f;
      const int gi = row_off + r0 + r;
      if (gi < B_) {  // t == 0 rows -> z0
        const size_t zi = ((size_t)e * B_ + gi) * L_ + j;
        const float z0 = qm_ + expf(ql_) * eps0[zi];
        const bf16 h = __float2bfloat16(z0);
        z0hi[zi] = h;
        z0lo[zi] = __float2bfloat16(z0 - __bfloat162float(h));
      }
    }
    for (int off = 32; off; off >>= 1) kl += __shfl_xor(kl, off, 64);
    if ((tid & 63) == 0) atomicAdd(&red[r], kl);
  }
  __syncthreads();
  if (tid < 16 && r0 + tid < rows) atomicAdd(&logqp[e], red[tid] * (1.0f / B_));
}

// ---------------- persistent scan kernel ----------------
struct ScanArgs {
  bf16* zhi; bf16* zlo;
  float* zP; bf16* zPb;
  bf16* fh1; bf16* fh2;
  float* gv;
  const float* axw;
  const bf16 *WzhiT, *WzloT;
  const bf16 *fw1T, *hw1T, *fw2T, *hw2T, *fw3T, *hw3T;
  const float *fb1, *hb1, *fb2, *hb2, *fb3, *hb3;
  const float *gw1, *gb1, *gw2, *gb2;
  const float* dw;
  float* logqp;
  bf16* zs_bf;
  unsigned* bar;
  int* gctr;
};

__device__ __forceinline__ void gsync(unsigned* bar, unsigned& ph, int tid) {
  __threadfence();
  __syncthreads();
  ++ph;
  if (tid == 0) {
    atomicAdd(bar, 1u);
    const unsigned tgt = ph * (unsigned)NWG;
    while (__hip_atomic_load(bar, __ATOMIC_RELAXED, __HIP_MEMORY_SCOPE_AGENT) < tgt)
      __builtin_amdgcn_s_sleep(2);
  }
  __syncthreads();
  __threadfence();
}

// P1: z = (zhi+zlo) @ (Whi+Wlo) + axw[t]  (split-bf16). 28 WGs.
__device__ void p1_gemm(const ScanArgs& a, int wg, int tid, int t, char* smem) {
  short* Ahi = (short*)smem;
  short* Alo = Ahi + 4096;
  short* Whi = Alo + 4096;
  short* Wlo = Whi + 4096;
  const int e = wg >> 2, nt = wg & 3;
  const int nbase = nt * 64;
  const short* zh = (const short*)a.zhi + (size_t)e * 50 * 256;
  const short* zl = (const short*)a.zlo + (size_t)e * 50 * 256;
  const short* wh = (const short*)a.WzhiT + (size_t)e * 65536 + (size_t)nbase * 256;
  const short* wl = (const short*)a.WzloT + (size_t)e * 65536 + (size_t)nbase * 256;
  const int wv = tid >> 6, lane = tid & 63, l15 = lane & 15, l4 = lane >> 4;
  const int wm0 = (wv >> 1) * 32, wn0 = (wv & 1) * 32;
  f32x4 acc[2][2] = {};
  for (int k0 = 0; k0 < 256; k0 += 64) {
    s8v vah[2], val[2], vwh[2], vwl[2];
#pragma unroll
    for (int i = 0; i < 2; ++i) {
      const int c = tid + i * 256, r = c >> 3, ck = c & 7;
      vah[i] = {}; val[i] = {};
      if (r < 50) {
        vah[i] = *(const s8v*)(zh + (size_t)r * 256 + k0 + ck * 8);
        val[i] = *(const s8v*)(zl + (size_t)r * 256 + k0 + ck * 8);
      }
      vwh[i] = *(const s8v*)(wh + (size_t)r * 256 + k0 + ck * 8);
      vwl[i] = *(const s8v*)(wl + (size_t)r * 256 + k0 + ck * 8);
    }
    __syncthreads();
#pragma unroll
    for (int i = 0; i < 2; ++i) {
      const int c = tid + i * 256, r = c >> 3;
      const int sw = ((c & 7) ^ (r & 7)) << 3;
      *(s8v*)(Ahi + r * 64 + sw) = vah[i];
      *(s8v*)(Alo + r * 64 + sw) = val[i];
      *(s8v*)(Whi + r * 64 + sw) = vwh[i];
      *(s8v*)(Wlo + r * 64 + sw) = vwl[i];
    }
    __syncthreads();
#pragma unroll
    for (int ks = 0; ks < 2; ++ks) {
      const int ck = ks * 4 + l4;
      s8v ah[2], al[2], bh[2], bl[2];
#pragma unroll
      for (int m = 0; m < 2; ++m) {
        const int r = wm0 + m * 16 + l15;
        const int sw = (ck ^ (r & 7)) << 3;
        ah[m] = *(const s8v*)(Ahi + r * 64 + sw);
        al[m] = *(const s8v*)(Alo + r * 64 + sw);
      }
#pragma unroll
      for (int n = 0; n < 2; ++n) {
        const int r = wn0 + n * 16 + l15;
        const int sw = (ck ^ (r & 7)) << 3;
        bh[n] = *(const s8v*)(Whi + r * 64 + sw);
        bl[n] = *(const s8v*)(Wlo + r * 64 + sw);
      }
#pragma unroll
      for (int m = 0; m < 2; ++m)
#pragma unroll
        for (int n = 0; n < 2; ++n) {
          acc[m][n] = __builtin_amdgcn_mfma_f32_16x16x32_bf16(ah[m], bh[n], acc[m][n], 0, 0, 0);
          acc[m][n] = __builtin_amdgcn_mfma_f32_16x16x32_bf16(al[m], bh[n], acc[m][n], 0, 0, 0);
          acc[m][n] = __builtin_amdgcn_mfma_f32_16x16x32_bf16(ah[m], bl[n], acc[m][n], 0, 0, 0);
        }
    }
    __syncthreads();
  }
#pragma unroll
  for (int n = 0; n < 2; ++n) {
    const int col = nbase + wn0 + n * 16 + l15;
#pragma unroll
    for (int m = 0; m < 2; ++m)
#pragma unroll
      for (int j = 0; j < 4; ++j) {
        const int row = wm0 + m * 16 + l4 * 4 + j;
        if (row < 50) {
          const float zv = acc[m][n][j] +
              a.axw[((size_t)e * TB_ + t * 50 + row) * 256 + col];
          const size_t rl = ((size_t)e * 50 + row) * 256 + col;
          a.zP[rl] = zv;
          a.zPb[rl] = __float2bfloat16(zv);
        }
      }
  }
}

// P2: fh1 = relu(zPb @ w1T + b1) for f,h. 96 WGs (6 mt x 16 ntile of 128 cols).
__device__ void p2_gemm(const ScanArgs& a, int wg, int tid, char* smem) {
  short* As = (short*)smem;
  short* Ws = (short*)smem + 4096;
  const int mt = wg >> 4, ntile = wg & 15;
  const int fb = ntile >> 3, nn = ntile & 7;
  const short* Ap = (const short*)a.zPb;
  const short* Wp = (const short*)(fb ? a.hw1T : a.fw1T) + (size_t)nn * 128 * 256;
  const int bm = mt * 64;
  const int wv = tid >> 6, lane = tid & 63, l15 = lane & 15, l4 = lane >> 4;
  const int wm0 = (wv >> 1) * 32, wn0 = (wv & 1) * 64;
  f32x4 acc[2][4] = {};
  for (int k0 = 0; k0 < 256; k0 += 64) {
    s8v av[2], wvv[4];
#pragma unroll
    for (int i = 0; i < 2; ++i) {          // FIX (round 3 bug): stage all 64 A rows
      const int c = tid + i * 256, r = c >> 3, ck = c & 7;
      av[i] = {};
      if (bm + r < EB_) av[i] = *(const s8v*)(Ap + (size_t)(bm + r) * 256 + k0 + ck * 8);
    }
#pragma unroll
    for (int i = 0; i < 4; ++i) {
      const int c = tid + i * 256, r = c >> 3, ck = c & 7;
      wvv[i] = *(const s8v*)(Wp + (size_t)r * 256 + k0 + ck * 8);
    }
    __syncthreads();
#pragma unroll
    for (int i = 0; i < 2; ++i) {
      const int c = tid + i * 256, r = c >> 3;
      *(s8v*)(As + r * 64 + (((c & 7) ^ (r & 7)) << 3)) = av[i];
    }
#pragma unroll
    for (int i = 0; i < 4; ++i) {
      const int c = tid + i * 256, r = c >> 3;
      *(s8v*)(Ws + r * 64 + (((c & 7) ^ (r & 7)) << 3)) = wvv[i];
    }
    __syncthreads();
#pragma unroll
    for (int ks = 0; ks < 2; ++ks) {
      const int ck = ks * 4 + l4;
      s8v af[2], bfr[4];
#pragma unroll
      for (int m = 0; m < 2; ++m) {
        const int r = wm0 + m * 16 + l15;
        af[m] = *(const s8v*)(As + r * 64 + ((ck ^ (r & 7)) << 3));
      }
#pragma unroll
      for (int n = 0; n < 4; ++n) {
        const int r = wn0 + n * 16 + l15;
        bfr[n] = *(const s8v*)(Ws + r * 64 + ((ck ^ (r & 7)) << 3));
      }
#pragma unroll
      for (int m = 0; m < 2; ++m)
#pragma unroll
        for (int n = 0; n < 4; ++n)
          acc[m][n] = __builtin_amdgcn_mfma_f32_16x16x32_bf16(af[m], bfr[n], acc[m][n], 0, 0, 0);
    }
    __syncthreads();
  }
  const float* bias = fb ? a.hb1 : a.fb1;
  bf16* C = a.fh1 + (size_t)fb * EB_ * 1024;
#pragma unroll
  for (int n = 0; n < 4; ++n) {
    const int col = nn * 128 + wn0 + n * 16 + l15;
    const float bv = bias[col];
#pragma unroll
    for (int m = 0; m < 2; ++m)
#pragma unroll
      for (int j = 0; j < 4; ++j) {
        const int row = bm + wm0 + m * 16 + l4 * 4 + j;
        if (row < EB_)
          C[(size_t)row * 1024 + col] = __float2bfloat16(fmaxf(acc[m][n][j] + bv, 0.f));
      }
  }
}

// P3: fh2 = tanh(fh1 @ w2T + b2). 192 WGs (6 mt x 32 ntile of 64 cols).
__device__ void p3_gemm(const ScanArgs& a, int wg, int tid, char* smem) {
  short* As = (short*)smem;
  short* Ws = (short*)smem + 4096;
  const int mt = wg >> 5, ntile = wg & 31;
  const int fb = ntile >> 4, nn = ntile & 15;
  const short* Ap = (const short*)a.fh1 + (size_t)fb * EB_ * 1024;
  const short* Wp = (const short*)(fb ? a.hw2T : a.fw2T) + (size_t)nn * 64 * 1024;
  const int bm = mt * 64;
  const int wv = tid >> 6, lane = tid & 63, l15 = lane & 15, l4 = lane >> 4;
  const int wm0 = (wv >> 1) * 32, wn0 = (wv & 1) * 32;
  f32x4 acc[2][2] = {};
  for (int k0 = 0; k0 < 1024; k0 += 64) {
    s8v av[2], wvv[2];
#pragma unroll
    for (int i = 0; i < 2; ++i) {
      const int c = tid + i * 256, r = c >> 3, ck = c & 7;
      av[i] = {};
      if (bm + r < EB_) av[i] = *(const s8v*)(Ap + (size_t)(bm + r) * 1024 + k0 + ck * 8);
      wvv[i] = *(const s8v*)(Wp + (size_t)r * 1024 + k0 + ck * 8);
    }
    __syncthreads();
#pragma unroll
    for (int i = 0; i < 2; ++i) {
      const int c = tid + i * 256, r = c >> 3;
      const int sw = ((c & 7) ^ (r & 7)) << 3;
      *(s8v*)(As + r * 64 + sw) = av[i];
      *(s8v*)(Ws + r * 64 + sw) = wvv[i];
    }
    __syncthreads();
#pragma unroll
    for (int ks = 0; ks < 2; ++ks) {
      const int ck = ks * 4 + l4;
      s8v af[2], bfr[2];
#pragma unroll
      for (int m = 0; m < 2; ++m) {
        const int r = wm0 + m * 16 + l15;
        af[m] = *(const s8v*)(As + r * 64 + ((ck ^ (r & 7)) << 3));
      }
#pragma unroll
      for (int n = 0; n < 2; ++n) {
        const int r = wn0 + n * 16 + l15;
        bfr[n] = *(const s8v*)(Ws + r * 64 + ((ck ^ (r & 7)) << 3));
      }
#pragma unroll
      for (int m = 0; m < 2; ++m)
#pragma unroll
        for (int n = 0; n < 2; ++n)
          acc[m][n] = __builtin_amdgcn_mfma_f32_16x16x32_bf16(af[m], bfr[n], acc[m][n], 0, 0, 0);
    }
    __syncthreads();
  }
  const float* bias = fb ? a.hb2 : a.fb2;
  bf16* C = a.fh2 + (size_t)fb * EB_ * 1024;
#pragma unroll
  for (int n = 0; n < 2; ++n) {
    const int col = nn * 64 + wn0 + n * 16 + l15;
    const float bv = bias[col];
#pragma unroll
    for (int m = 0; m < 2; ++m)
#pragma unroll
      for (int j = 0; j < 4; ++j) {
        const int row = bm + wm0 + m * 16 + l4 * 4 + j;
        if (row < EB_)
          C[(size_t)row * 1024 + col] = __float2bfloat16(tanhf(acc[m][n][j] + bv));
      }
  }
}

// P4+P5: fv/hv GEMM (K=1024) + epilogue. 44 WGs (11 rt x 4 lt).
__device__ void p45(const ScanArgs& a, int wg, int tid, int t, char* smem) {
  short* Af = (short*)smem;          // 32x64
  short* Ah = Af + 2048;
  short* Wf = Ah + 2048;             // 64x64
  short* Wh = Wf + 4096;
  const int rt = wg >> 2, lt = wg & 3;
  const int r0 = rt * 32, lc = lt * 64;
  const short* Apf = (const short*)a.fh2;
  const short* Aph = (const short*)a.fh2 + (size_t)EB_ * 1024;
  const int wv = tid >> 6, lane = tid & 63, l15 = lane & 15, l4 = lane >> 4;
  const int wn0 = wv * 16;
  f32x4 aF[2] = {}, aH[2] = {};
  for (int k0 = 0; k0 < 1024; k0 += 64) {
    s8v vaf, vah, vwf[2], vwh[2];
    {
      const int c = tid, r = c >> 3, ck = c & 7;
      vaf = {}; vah = {};
      if (r0 + r < EB_) {
        vaf = *(const s8v*)(Apf + (size_t)(r0 + r) * 1024 + k0 + ck * 8);
        vah = *(const s8v*)(Aph + (size_t)(r0 + r) * 1024 + k0 + ck * 8);
      }
    }
#pragma unroll
    for (int i = 0; i < 2; ++i) {
      const int c = tid + i * 256, r = c >> 3, ck = c & 7;
      vwf[i] = *(const s8v*)((const short*)a.fw3T + (size_t)(lc + r) * 1024 + k0 + ck * 8);
      vwh[i] = *(const s8v*)((const short*)a.hw3T + (size_t)(lc + r) * 1024 + k0 + ck * 8);
    }
    __syncthreads();
    {
      const int c = tid, r = c >> 3;
      const int sw = ((c & 7) ^ (r & 7)) << 3;
      *(s8v*)(Af + r * 64 + sw) = vaf;
      *(s8v*)(Ah + r * 64 + sw) = vah;
    }
#pragma unroll
    for (int i = 0; i < 2; ++i) {
      const int c = tid + i * 256, r = c >> 3;
      const int sw = ((c & 7) ^ (r & 7)) << 3;
      *(s8v*)(Wf + r * 64 + sw) = vwf[i];
      *(s8v*)(Wh + r * 64 + sw) = vwh[i];
    }
    __syncthreads();
#pragma unroll
    for (int ks = 0; ks < 2; ++ks) {
      const int ck = ks * 4 + l4;
      const int rb = wn0 + l15;
      const int swb = (ck ^ (rb & 7)) << 3;
      s8v bf_ = *(const s8v*)(Wf + rb * 64 + swb);
      s8v bh_ = *(const s8v*)(Wh + rb * 64 + swb);
#pragma unroll
      for (int m = 0; m < 2; ++m) {
        const int ar = m * 16 + l15;
        const int swa = (ck ^ (ar & 7)) << 3;
        s8v af_ = *(const s8v*)(Af + ar * 64 + swa);
        s8v ah_ = *(const s8v*)(Ah + ar * 64 + swa);
        aF[m] = __builtin_amdgcn_mfma_f32_16x16x32_bf16(af_, bf_, aF[m], 0, 0, 0);
        aH[m] = __builtin_amdgcn_mfma_f32_16x16x32_bf16(ah_, bh_, aH[m], 0, 0, 0);
      }
    }
    __syncthreads();
  }
  const int col = lc + wn0 + l15;
  const float fb3v = a.fb3[col];
  const float hb3v = a.hb3[col];
  const int e0 = r0 / 50;
  const int e1 = (r0 + 31) / 50;
  float s0 = 0.f, s1 = 0.f;
#pragma unroll
  for (int m = 0; m < 2; ++m)
#pragma unroll
    for (int j = 0; j < 4; ++j) {
      const int row = r0 + m * 16 + l4 * 4 + j;
      if (row < EB_) {
        const float fv = aF[m][j] + fb3v;
        const float hv = aH[m][j] + hb3v;
        const size_t rl = (size_t)row * 256 + col;
        const float gvv = a.gv[rl];
        const float u = (fv - hv) / gvv;
        const int e = row / 50;
        ((e == e0) ? s0 : s1) += u * u;
        const float znew = a.zP[rl] + 0.1f * fv + gvv * (SQRTH * a.dw[(size_t)t * 89600 + rl]);
        const bf16 h = __float2bfloat16(znew);
        a.zhi[rl] = h;
        a.zlo[rl] = __float2bfloat16(znew - __bfloat162float(h));
        const int b = row - e * 50;
        a.zs_bf[(((size_t)e * T_ + t) * B_ + b) * 256 + col] = h;
      }
    }
#pragma unroll
  for (int o = 32; o; o >>= 1) {
    s0 += __shfl_xor(s0, o, 64);
    s1 += __shfl_xor(s1, o, 64);
  }
  if (lane == 0) {
    atomicAdd(&a.logqp[e0], 1e-3f * s0);
    if (e1 != e0) atomicAdd(&a.logqp[e1], 1e-3f * s1);
  }
}

// g unit: one (l, row-half). fp16 packed, f32 accumulate.
__device__ void g_unit(const ScanArgs& a, int u, int tid) {
  const int l = u >> 1, hf = u & 1;
  const int wv = tid >> 6, lane = tid & 63;
  f16x2 w1h[8], b1h[8], w2h[8];
  {
    const float4* q1 = (const float4*)(a.gw1 + (size_t)l * 1024 + lane * 16);
    const float4* q2 = (const float4*)(a.gb1 + (size_t)l * 1024 + lane * 16);
    const float4* q3 = (const float4*)(a.gw2 + (size_t)l * 1024 + lane * 16);
#pragma unroll
    for (int q = 0; q < 4; ++q) {
      const float4 v1 = q1[q], v2 = q2[q], v3 = q3[q];
      w1h[2 * q] = f16x2{(_Float16)v1.x, (_Float16)v1.y};
      w1h[2 * q + 1] = f16x2{(_Float16)v1.z, (_Float16)v1.w};
      b1h[2 * q] = f16x2{(_Float16)v2.x, (_Float16)v2.y};
      b1h[2 * q + 1] = f16x2{(_Float16)v2.z, (_Float16)v2.w};
      w2h[2 * q] = f16x2{(_Float16)v3.x, (_Float16)v3.y};
      w2h[2 * q + 1] = f16x2{(_Float16)v3.z, (_Float16)v3.w};
    }
  }
  const float gb2v = a.gb2[l];
  const f16x2 zz = {};
  const int rbeg = hf * 176 + wv * 44;
  int rend = hf * 176 + (wv + 1) * 44;
  if (rend > EB_) rend = EB_;
  for (int r = rbeg; r < rend; ++r) {
    const float zf = a.zP[(size_t)r * 256 + l];
    const _Float16 zh = (_Float16)zf;
    const f16x2 z2 = {zh, zh};
    float acc = 0.f;
#pragma unroll
    for (int i = 0; i < 8; ++i) {
      f16x2 tt = z2 * w1h[i] + b1h[i];
#if __has_builtin(__builtin_elementwise_max)
      tt = __builtin_elementwise_max(tt, zz);
#else
      tt[0] = tt[0] > (_Float16)0 ? tt[0] : (_Float16)0;
      tt[1] = tt[1] > (_Float16)0 ? tt[1] : (_Float16)0;
#endif
#if __has_builtin(__builtin_amdgcn_fdot2)
      acc = __builtin_amdgcn_fdot2(tt, w2h[i], acc, false);
#else
      acc += (float)tt[0] * (float)w2h[i][0] + (float)tt[1] * (float)w2h[i][1];
#endif
    }
#pragma unroll
    for (int o = 32; o; o >>= 1) acc += __shfl_xor(acc, o, 64);
    if (lane == 0) a.gv[(size_t)r * 256 + l] = acc + gb2v;
  }
}

__global__ __launch_bounds__(256, 1) void scan_kernel(ScanArgs a) {
  __shared__ __align__(16) char smem[32768];
  __shared__ int s_u;
  const int wg = blockIdx.x, tid = threadIdx.x;
  unsigned ph = 0;
  for (int t = 0; t < T_; ++t) {
    if (wg == 60 && tid == 0)
      __hip_atomic_store(a.gctr, 0, __ATOMIC_RELAXED, __HIP_MEMORY_SCOPE_AGENT);
    if (wg < 28) p1_gemm(a, wg, tid, t, smem);
    gsync(a.bar, ph, tid);
    // ---- P2 + g work-stealing ----
    if (wg < 96) p2_gemm(a, wg, tid, smem);
    for (;;) {
      if (tid == 0) s_u = atomicAdd(a.gctr, 1);
      __syncthreads();
      const int u = s_u;
      __syncthreads();
      if (u >= 512) break;
      g_unit(a, u, tid);
    }
    gsync(a.bar, ph, tid);
    // ---- P3 + g work-stealing (pool usually drained already) ----
    if (wg < 192) p3_gemm(a, wg, tid, smem);
    for (;;) {
      if (tid == 0) s_u = atomicAdd(a.gctr, 1);
      __syncthreads();
      const int u = s_u;
      __syncthreads();
      if (u >= 512) break;
      g_unit(a, u, tid);
    }
    gsync(a.bar, ph, tid);
    // ---- P4+P5 ----
    if (wg < 44) p45(a, wg, tid, t, smem);
    gsync(a.bar, ph, tid);
  }
}

__global__ void init_kernel(float* logqp, unsigned* bar, int* gctr) {
  if (threadIdx.x < E_) logqp[threadIdx.x] = 0.f;
  if (threadIdx.x == 63) { *bar = 0u; *gctr = 0; }
}

extern "C" void kernel_launch(void* const* d_in, const int* in_sizes, int n_in,
                              void* d_out, int out_size, void* d_ws, size_t ws_size,
                              hipStream_t stream) {
  (void)in_sizes; (void)n_in; (void)out_size;
  const float* enc_w1 = (const float*)d_in[0];
  const float* enc_b1 = (const float*)d_in[1];
  const float* enc_w2 = (const float*)d_in[2];
  const float* enc_b2 = (const float*)d_in[3];
  const float* enc_w3 = (const float*)d_in[4];
  const float* enc_b3 = (const float*)d_in[5];
  const float* qz0_w  = (const float*)d_in[6];
  const float* qz0_b  = (const float*)d_in[7];
  const float* act_w  = (const float*)d_in[8];
  const float* act_b  = (const float*)d_in[9];
  const float* proj_w1 = (const float*)d_in[10];
  const float* proj_b1 = (const float*)d_in[11];
  const float* proj_w2 = (const float*)d_in[12];
  const float* proj_b2 = (const float*)d_in[13];
  const float* proj_w3 = (const float*)d_in[14];
  const float* proj_b3 = (const float*)d_in[15];
  const float* f_w1 = (const float*)d_in[16];
  const float* f_b1 = (const float*)d_in[17];
  const float* f_w2 = (const float*)d_in[18];
  const float* f_b2 = (const float*)d_in[19];
  const float* f_w3 = (const float*)d_in[20];
  const float* f_b3 = (const float*)d_in[21];
  const float* h_w1 = (const float*)d_in[22];
  const float* h_b1 = (const float*)d_in[23];
  const float* h_w2 = (const float*)d_in[24];
  const float* h_b2 = (const float*)d_in[25];
  const float* h_w3 = (const float*)d_in[26];
  const float* h_b3 = (const float*)d_in[27];
  const float* g_w1 = (const float*)d_in[28];
  const float* g_b1 = (const float*)d_in[29];
  const float* g_w2 = (const float*)d_in[30];
  const float* g_b2 = (const float*)d_in[31];
  const float* pz0_mean   = (const float*)d_in[32];
  const float* pz0_logstd = (const float*)d_in[33];
  const float* xs      = (const float*)d_in[34];
  const float* actions = (const float*)d_in[35];
  const float* eps_z0  = (const float*)d_in[36];
  const float* dw      = (const float*)d_in[37];

  float* out = (float*)d_out;
  float* logqp = out;
  float* pred = out + E_;

  char* base = (char*)d_ws;
  size_t off = 0;
  auto alloc = [&](size_t bytes) {
    void* p = base + off;
    off = (off + bytes + 255) & ~(size_t)255;
    return p;
  };
  bf16* zhi    = (bf16*)alloc((size_t)EB_ * 256 * 2);
  bf16* zlo    = (bf16*)alloc((size_t)EB_ * 256 * 2);
  float* zP    = (float*)alloc((size_t)EB_ * 256 * 4);
  bf16* zPb    = (bf16*)alloc((size_t)EB_ * 256 * 2);
  bf16* fh1    = (bf16*)alloc((size_t)2 * EB_ * 1024 * 2);
  bf16* fh2    = (bf16*)alloc((size_t)2 * EB_ * 1024 * 2);
  float* gvb   = (float*)alloc((size_t)EB_ * 256 * 4);
  bf16* zs_bf  = (bf16*)alloc((size_t)E_ * T_ * B_ * 256 * 2);
  float* axw   = (float*)alloc((size_t)E_ * TB_ * 256 * 4);
  bf16* ax_bf  = (bf16*)alloc((size_t)E_ * TB_ * 192 * 2);
  bf16* waxT   = (bf16*)alloc((size_t)E_ * 256 * 192 * 2);
  bf16* WzhiT  = (bf16*)alloc((size_t)E_ * 256 * 256 * 2);
  bf16* WzloT  = (bf16*)alloc((size_t)E_ * 256 * 256 * 2);
  bf16* xs_bf  = (bf16*)alloc((size_t)E_ * TB_ * D_ * 2);
  bf16* ew1T = (bf16*)alloc((size_t)E_ * D_ * H_ * 2);
  bf16* ew2T = (bf16*)alloc((size_t)E_ * H_ * H_ * 2);
  bf16* ew3T = (bf16*)alloc((size_t)E_ * H_ * C_ * 2);
  bf16* pw1T = (bf16*)alloc((size_t)E_ * L_ * H_ * 2);
  bf16* pw2T = (bf16*)alloc((size_t)E_ * H_ * H_ * 2);
  bf16* pw3T = (bf16*)alloc((size_t)E_ * H_ * D_ * 2);
  bf16* fw1T = (bf16*)alloc((size_t)L_ * H_ * 2);
  bf16* fw2T = (bf16*)alloc((size_t)H_ * H_ * 2);
  bf16* fw3T = (bf16*)alloc((size_t)H_ * L_ * 2);
  bf16* hw1T = (bf16*)alloc((size_t)L_ * H_ * 2);
  bf16* hw2T = (bf16*)alloc((size_t)H_ * H_ * 2);
  bf16* hw3T = (bf16*)alloc((size_t)H_ * L_ * 2);
  unsigned* bar = (unsigned*)alloc(256);
  int* gctr = (int*)alloc(256);
  const size_t per_row = (size_t)E_ * (H_ * 2 * 2 + C_ * 4);
  size_t remain = (ws_size > off + 4096) ? (ws_size - off - 4096) : 0;
  int CH = (int)(remain / per_row);
  if (CH > 2500) CH = 2500;
  if (CH < 64) CH = 64;
  bf16* bufA = (bf16*)alloc((size_t)E_ * CH * H_ * 2);
  bf16* bufB = (bf16*)alloc((size_t)E_ * CH * H_ * 2);
  float* bufC = (float*)alloc((size_t)E_ * CH * C_ * 4);

  init_kernel<<<dim3(1), dim3(64), 0, stream>>>(logqp, bar, gctr);

  const dim3 cb(256);
  cvt_kernel<<<dim3((E_ * TB_ * D_ / 4 + 255) / 256), cb, 0, stream>>>(xs, xs_bf, E_ * TB_ * D_ / 4);
  cvtT_kernel<<<dim3(H_ / 32, D_ / 32, E_), cb, 0, stream>>>(enc_w1, ew1T, D_, H_, (long)D_ * H_, (long)D_ * H_);
  cvtT_kernel<<<dim3(H_ / 32, H_ / 32, E_), cb, 0, stream>>>(enc_w2, ew2T, H_, H_, (long)H_ * H_, (long)H_ * H_);
  cvtT_kernel<<<dim3(C_ / 32, H_ / 32, E_), cb, 0, stream>>>(enc_w3, ew3T, H_, C_, (long)H_ * C_, (long)H_ * C_);
  cvtT_kernel<<<dim3(H_ / 32, L_ / 32, E_), cb, 0, stream>>>(proj_w1, pw1T, L_, H_, (long)L_ * H_, (long)L_ * H_);
  cvtT_kernel<<<dim3(H_ / 32, H_ / 32, E_), cb, 0, stream>>>(proj_w2, pw2T, H_, H_, (long)H_ * H_, (long)H_ * H_);
  cvtT_kernel<<<dim3(D_ / 32, H_ / 32, E_), cb, 0, stream>>>(proj_w3, pw3T, H_, D_, (long)H_ * D_, (long)H_ * D_);
  cvtT_kernel<<<dim3(H_ / 32, L_ / 32, 1), cb, 0, stream>>>(f_w1, fw1T, L_, H_, 0, 0);
  cvtT_kernel<<<dim3(H_ / 32, H_ / 32, 1), cb, 0, stream>>>(f_w2, fw2T, H_, H_, 0, 0);
  cvtT_kernel<<<dim3(L_ / 32, H_ / 32, 1), cb, 0, stream>>>(f_w3, fw3T, H_, L_, 0, 0);
  cvtT_kernel<<<dim3(H_ / 32, L_ / 32, 1), cb, 0, stream>>>(h_w1, hw1T, L_, H_, 0, 0);
  cvtT_kernel<<<dim3(H_ / 32, H_ / 32, 1), cb, 0, stream>>>(h_w2, hw2T, H_, H_, 0, 0);
  cvtT_kernel<<<dim3(L_ / 32, H_ / 32, 1), cb, 0, stream>>>(h_w3, hw3T, H_, L_, 0, 0);
  ax_build<<<dim3((E_ * TB_ * 192 + 255) / 256), cb, 0, stream>>>(actions, xs, ax_bf);
  waxT_build<<<dim3((E_ * 256 * 192 + 255) / 256), cb, 0, stream>>>(act_w, waxT);
  wsplitT_build<<<dim3((E_ * 256 * 256 + 255) / 256), cb, 0, stream>>>(act_w, WzhiT, WzloT);

  BG g;
  // axw = ax @ WaxT + act_b
  for (int e = 0; e < E_; ++e) {
    g.A[e] = ax_bf + (size_t)e * TB_ * 192;
    g.W[e] = waxT + (size_t)e * 256 * 192;
    g.bias[e] = act_b + (size_t)e * 256;
    g.Cf[e] = axw + (size_t)e * TB_ * 256;
  }
  bgemm<128, 0, 0><<<dim3((TB_ + 127) / 128, 2, E_), 256, 0, stream>>>(g, TB_, 192, 192, 192, 256);

  // ---- Phase A: encoder + q/KL (+z0 split) ----
  for (int c = 0; c < TB_; c += CH) {
    const int rows = (TB_ - c < CH) ? (TB_ - c) : CH;
    const int mt = (rows + 127) / 128;
    for (int e = 0; e < E_; ++e) {
      g.A[e] = xs_bf + ((size_t)e * TB_ + c) * D_;
      g.W[e] = ew1T + (size_t)e * D_ * H_;
      g.bias[e] = enc_b1 + (size_t)e * H_;
      g.Cb[e] = bufA + (size_t)e * CH * H_;
    }
    bgemm<128, 1, 1><<<dim3(mt, H_ / 128, E_), 256, 0, stream>>>(g, rows, D_, D_, D_, H_);
    for (int e = 0; e < E_; ++e) {
      g.A[e] = bufA + (size_t)e * CH * H_;
      g.W[e] = ew2T + (size_t)e * H_ * H_;
      g.bias[e] = enc_b2 + (size_t)e * H_;
      g.Cb[e] = bufB + (size_t)e * CH * H_;
    }
    bgemm<128, 1, 1><<<dim3(mt, H_ / 128, E_), 256, 0, stream>>>(g, rows, H_, H_, H_, H_);
    for (int e = 0; e < E_; ++e) {
      g.A[e] = bufB + (size_t)e * CH * H_;
      g.W[e] = ew3T + (size_t)e * H_ * C_;
      g.bias[e] = enc_b3 + (size_t)e * C_;
      g.Cf[e] = bufC + (size_t)e * CH * C_;
    }
    bgemm<128, 0, 0><<<dim3(mt, C_ / 128, E_), 256, 0, stream>>>(g, rows, H_, H_, H_, C_);
    qkl_kernel<<<dim3((rows + 15) / 16, E_), 256, 0, stream>>>(
        bufC, rows, c, CH * C_, qz0_w, qz0_b, pz0_mean, pz0_logstd, eps_z0,
        zhi, zlo, logqp);
  }

  // ---- Persistent cooperative scan ----
  ScanArgs sa;
  sa.zhi = zhi; sa.zlo = zlo; sa.zP = zP; sa.zPb = zPb;
  sa.fh1 = fh1; sa.fh2 = fh2; sa.gv = gvb; sa.axw = axw;
  sa.WzhiT = WzhiT; sa.WzloT = WzloT;
  sa.fw1T = fw1T; sa.hw1T = hw1T; sa.fw2T = fw2T; sa.hw2T = hw2T;
  sa.fw3T = fw3T; sa.hw3T = hw3T;
  sa.fb1 = f_b1; sa.hb1 = h_b1; sa.fb2 = f_b2; sa.hb2 = h_b2;
  sa.fb3 = f_b3; sa.hb3 = h_b3;
  sa.gw1 = g_w1; sa.gb1 = g_b1; sa.gw2 = g_w2; sa.gb2 = g_b2;
  sa.dw = dw; sa.logqp = logqp; sa.zs_bf = zs_bf; sa.bar = bar; sa.gctr = gctr;
  void* params[] = {(void*)&sa};
  if (hipLaunchCooperativeKernel((const void*)scan_kernel, dim3(NWG), dim3(256),
                                 params, 0, stream) != hipSuccess) {
    scan_kernel<<<dim3(NWG), dim3(256), 0, stream>>>(sa);
  }

  // ---- Projector ----
  for (int c = 0; c < TB_; c += CH) {
    const int rows = (TB_ - c < CH) ? (TB_ - c) : CH;
    const int mt = (rows + 127) / 128;
    for (int e = 0; e < E_; ++e) {
      g.A[e] = zs_bf + ((size_t)e * T_ * B_ + c) * L_;
      g.W[e] = pw1T + (size_t)e * L_ * H_;
      g.bias[e] = proj_b1 + (size_t)e * H_;
      g.Cb[e] = bufA + (size_t)e * CH * H_;
    }
    bgemm<128, 2, 1><<<dim3(mt, H_ / 128, E_), 256, 0, stream>>>(g, rows, L_, L_, L_, H_);
    for (int e = 0; e < E_; ++e) {
      g.A[e] = bufA + (size_t)e * CH * H_;
      g.W[e] = pw2T + (size_t)e * H_ * H_;
      g.bias[e] = proj_b2 + (size_t)e * H_;
      g.Cb[e] = bufB + (size_t)e * CH * H_;
    }
    bgemm<128, 2, 1><<<dim3(mt, H_ / 128, E_), 256, 0, stream>>>(g, rows, H_, H_, H_, H_);
    for (int e = 0; e < E_; ++e) {
      g.A[e] = bufB + (size_t)e * CH * H_;
      g.W[e] = pw3T + (size_t)e * H_ * D_;
      g.bias[e] = proj_b3 + (size_t)e * D_;
      g.Cf[e] = pred + ((size_t)e * TB_ + c) * D_;
    }
    bgemm<128, 0, 0><<<dim3(mt, D_ / 128, E_), 256, 0, stream>>>(g, rows, H_, H_, H_, D_);
  }
}